// Round 1
// baseline (1264.365 us; speedup 1.0000x reference)
//
#include <hip/hip_runtime.h>
#include <hip/hip_bf16.h>

// FeatureBooster: out = x * sigmoid(2 * (relu(x@W1) @ W2))
// x: [N,256] fp32, W1: [256,16] fp32, W2: [16,256] fp32, out: [N,256] fp32.
// Memory-bound: 1.024 GB irreducible traffic -> ~163 us floor at 6.3 TB/s.
//
// Layout: one wave per row. lane l owns columns [4l, 4l+4): one float4
// load + one float4 store per lane per row (coalesced, 1 KB each).
// W1 rows [4l,4l+4) (64 floats) and W2 cols [4l,4l+4) (64 floats) are
// preloaded into registers once per wave (W is only 16 KB total, L2-hot).
//
// h[16] = relu(row @ W1) needs a 64-lane reduction. Full butterfly would be
// 96 shuffles/row (DS-pipe bound). Halving butterfly instead: at each step
// each lane keeps half its values and folds in the partner's half
// (16->8->4->2->1 over xor masks 1,2,4,8), then 2 scalar butterfly steps
// (xor 16,32). ~17 shuffles/row. Lane l ends holding the full sum of
// h[bitrev4(l&15)]; lanes 0..15 write to LDS, all lanes read back 16 floats
// (b128 broadcast reads, conflict-free).

__global__ __launch_bounds__(256, 2) void fb_kernel(
    const float* __restrict__ x,
    const float* __restrict__ W1,
    const float* __restrict__ W2,
    float* __restrict__ out,
    int n)
{
    const int lane = threadIdx.x & 63;
    const int wslot = threadIdx.x >> 6;                  // wave within block
    const int gwave = blockIdx.x * 4 + wslot;            // global wave id
    const int nwaves = gridDim.x * 4;

    // ---- preload per-lane weight slices into registers ----
    float w1[4][16];   // w1[r][j] = W1[4*lane + r][j]
    {
        const float4* W1v = reinterpret_cast<const float4*>(W1); // [256][4 x float4]
#pragma unroll
        for (int r = 0; r < 4; ++r) {
#pragma unroll
            for (int q = 0; q < 4; ++q) {
                float4 t = W1v[(4 * lane + r) * 4 + q];
                w1[r][4 * q + 0] = t.x;
                w1[r][4 * q + 1] = t.y;
                w1[r][4 * q + 2] = t.z;
                w1[r][4 * q + 3] = t.w;
            }
        }
    }
    float w2[16][4];   // w2[j][r] = W2[j][4*lane + r]
#pragma unroll
    for (int j = 0; j < 16; ++j) {
        float4 t = *reinterpret_cast<const float4*>(&W2[j * 256 + 4 * lane]);
        w2[j][0] = t.x; w2[j][1] = t.y; w2[j][2] = t.z; w2[j][3] = t.w;
    }

    __shared__ __align__(16) float hbuf[4][16];

    // lane l (l<16) holds h[jmap] after the halving reduction
    const int jmap = ((lane & 1) << 3) | ((lane & 2) << 1) |
                     ((lane & 4) >> 1) | ((lane & 8) >> 3);

    long long row = gwave;
    if (row >= n) return;

    const float* xp = x + row * 256LL + 4 * lane;
    float4 xv = *reinterpret_cast<const float4*>(xp);

    while (true) {
        long long nrow = row + nwaves;
        float4 xnext;
        bool have_next = (nrow < n);
        if (have_next) {
            xnext = *reinterpret_cast<const float4*>(x + nrow * 256LL + 4 * lane);
        }

        // ---- pass 1: per-lane partials of h[16] ----
        float p[16];
#pragma unroll
        for (int j = 0; j < 16; ++j) {
            float a = xv.x * w1[0][j];
            a = fmaf(xv.y, w1[1][j], a);
            a = fmaf(xv.z, w1[2][j], a);
            a = fmaf(xv.w, w1[3][j], a);
            p[j] = a;
        }

        // ---- halving butterfly reduction across 64 lanes ----
        float s8[8];
        {
            const bool b = (lane & 1) != 0;
            float snd[8];
#pragma unroll
            for (int j = 0; j < 8; ++j) snd[j] = b ? p[j] : p[j + 8];
#pragma unroll
            for (int j = 0; j < 8; ++j) snd[j] = __shfl_xor(snd[j], 1, 64);
#pragma unroll
            for (int j = 0; j < 8; ++j) s8[j] = (b ? p[j + 8] : p[j]) + snd[j];
        }
        float s4[4];
        {
            const bool b = (lane & 2) != 0;
            float snd[4];
#pragma unroll
            for (int j = 0; j < 4; ++j) snd[j] = b ? s8[j] : s8[j + 4];
#pragma unroll
            for (int j = 0; j < 4; ++j) snd[j] = __shfl_xor(snd[j], 2, 64);
#pragma unroll
            for (int j = 0; j < 4; ++j) s4[j] = (b ? s8[j + 4] : s8[j]) + snd[j];
        }
        float s2[2];
        {
            const bool b = (lane & 4) != 0;
            float snd[2];
#pragma unroll
            for (int j = 0; j < 2; ++j) snd[j] = b ? s4[j] : s4[j + 2];
#pragma unroll
            for (int j = 0; j < 2; ++j) snd[j] = __shfl_xor(snd[j], 4, 64);
#pragma unroll
            for (int j = 0; j < 2; ++j) s2[j] = (b ? s4[j + 2] : s4[j]) + snd[j];
        }
        float s1;
        {
            const bool b = (lane & 8) != 0;
            float snd = b ? s2[0] : s2[1];
            snd = __shfl_xor(snd, 8, 64);
            s1 = (b ? s2[1] : s2[0]) + snd;
        }
        s1 += __shfl_xor(s1, 16, 64);
        s1 += __shfl_xor(s1, 32, 64);
        s1 = fmaxf(s1, 0.0f);   // ReLU

        // ---- broadcast h[16] to all lanes via LDS ----
        if (lane < 16) hbuf[wslot][jmap] = s1;
        __builtin_amdgcn_wave_barrier();
        float h[16];
        {
            const float4* hb = reinterpret_cast<const float4*>(&hbuf[wslot][0]);
#pragma unroll
            for (int q = 0; q < 4; ++q) {
                float4 t = hb[q];
                h[4 * q + 0] = t.x;
                h[4 * q + 1] = t.y;
                h[4 * q + 2] = t.z;
                h[4 * q + 3] = t.w;
            }
        }
        __builtin_amdgcn_wave_barrier();

        // ---- pass 2: s_c = h @ W2 for this lane's 4 columns ----
        float sc[4];
#pragma unroll
        for (int r = 0; r < 4; ++r) {
            float a = h[0] * w2[0][r];
#pragma unroll
            for (int j = 1; j < 16; ++j) a = fmaf(h[j], w2[j][r], a);
            sc[r] = a;
        }

        // ---- gate: out = x * sigmoid(2*sc) ----
        float4 o;
        {
            float e0 = __expf(-2.0f * sc[0]);
            float e1 = __expf(-2.0f * sc[1]);
            float e2 = __expf(-2.0f * sc[2]);
            float e3 = __expf(-2.0f * sc[3]);
            o.x = xv.x * __builtin_amdgcn_rcpf(1.0f + e0);
            o.y = xv.y * __builtin_amdgcn_rcpf(1.0f + e1);
            o.z = xv.z * __builtin_amdgcn_rcpf(1.0f + e2);
            o.w = xv.w * __builtin_amdgcn_rcpf(1.0f + e3);
        }
        *reinterpret_cast<float4*>(out + row * 256LL + 4 * lane) = o;

        if (!have_next) break;
        row = nrow;
        xv = xnext;
    }
}

extern "C" void kernel_launch(void* const* d_in, const int* in_sizes, int n_in,
                              void* d_out, int out_size, void* d_ws, size_t ws_size,
                              hipStream_t stream) {
    const float* x  = (const float*)d_in[0];
    const float* W1 = (const float*)d_in[1];
    const float* W2 = (const float*)d_in[2];
    float* out = (float*)d_out;
    const int n = in_sizes[0] / 256;   // 500000 rows

    // 2048 blocks x 4 waves = 8192 waves, ~61 rows per wave (grid-stride).
    fb_kernel<<<2048, 256, 0, stream>>>(x, W1, W2, out, n);
}